// Round 4
// baseline (157.698 us; speedup 1.0000x reference)
//
#include <hip/hip_runtime.h>
#include <math.h>

typedef unsigned long long ull;

// Problem constants (from setup_inputs): B=64, G=4999, P=50
constexpr int Bc = 64;
constexpr int Gc = 4999;
constexpr int Pc = 50;

constexpr int N8 = 8192;             // padded row size (single bitonic sort)
constexpr int E  = 8;                // elems per thread
constexpr int T  = 1024;             // threads per block
constexpr int LPW4  = 21;            // genes per lane in es phase (256 chunks * 21 = 5376 >= G; 21 coprime 32 banks)
constexpr int QSPAN = 64 * LPW4;     // genes per quarter = 1344
constexpr ull PADKEY = 0xFFFFFFFFFFFFFFFFull;

__device__ __forceinline__ ull shfl_xor64(ull v, int lm) {
    int lo = __shfl_xor((int)(unsigned)(v & 0xFFFFFFFFull), lm, 64);
    int hi = __shfl_xor((int)(unsigned)(v >> 32), lm, 64);
    return ((ull)(unsigned)hi << 32) | (unsigned)lo;
}

// ---------------------------------------------------------------------------
// SINGLE-LAUNCH kernel. Grid (4,64) x 1024 (16 waves, 1 block/CU).
// Block (pg,b):
//   Phase 0: pack 13-bit pathway window (pathways pg*13..) by gene -> pbwin
//            (260 KB coalesced reads, L2-hot since all blocks share 1 MB).
//   Phase 1: 8192-wide bitonic sort of row b (8 elems/thread; key =
//            (~m)<<32|idx, unique -> ascending u64 == stable argsort(-x)).
//            Register stages j<=4, wave-shuffle j=8..256, LDS j>=512.
//            Rank == final position: NO binary searches, NO runs round-trip.
//            Sort duplicated x4 across pg-blocks, but 256 blocks = 1/CU so
//            it runs fully parallel; it buys one-launch totality.
//   Phase 2: decode keys (held in regs across the union-alias barrier) ->
//            swq[pos]=|v|^0.25, sm16[pos]=pbwin[idx]  (pos<G for real keys).
//   Phase 3: es phase (R3-verified): wave w = pathway quad qg=w>>2 x gene
//            quarter h=w&3, lane chunk 21 genes (coprime 32 banks).
// LDS: union{key[8192] (64K) | swq+sm16 (30K)} + pbwin 10K + combine ~1.8K
//      ~= 78 KB -> 1 block/CU, 16 waves (4/SIMD).
// No workspace use at all.
// ---------------------------------------------------------------------------
struct SMem {
    union U {
        ull key[N8];                        // 65536 B (sort)
        struct S {
            float          swq[5120];       // 20480 B (post-sort)
            unsigned short sm16[5120];      // 10240 B
        } s;
    } u;
    unsigned short pbwin[5120];             // 10240 B: 13-bit window by gene
    double cSW[4][4][4];
    int    cSH[4][4][4];
    double cBV[4][4][4];
    double cBR[4][4][4];
};

__global__ __launch_bounds__(1024) void mono_es(
    const float* __restrict__ expr, const float* __restrict__ pathway,
    float* __restrict__ out, int B, int P, int G)
{
    __shared__ SMem sm;
    const int pg  = blockIdx.x;
    const int b   = blockIdx.y;
    const int tid = threadIdx.x;
    const int pbeg = pg * 13;
    const int pend = (pbeg + 13 < P) ? (pbeg + 13) : P;
    const int base = tid * E;

    // ---- Phase 0: pathway window bits by gene (visibility guaranteed by
    //      the sort's barriers before any gather in Phase 2) ----
    for (int g = tid; g < G; g += T) {
        unsigned mask = 0;
#pragma unroll
        for (int p = 0; p < 13; ++p) {
            int pp = pbeg + p;
            if (pp < Pc && pathway[(size_t)pp * G + g] > 0.0f) mask |= (1u << p);
        }
        sm.pbwin[g] = (unsigned short)mask;
    }

    // ---- Phase 1: load + key-encode + 8192 bitonic sort ----
    const float* row = expr + (size_t)b * G;
    ull v[E];
#pragma unroll
    for (int o = 0; o < E; ++o) {
        int i = base + o;
        if (i < G) {
            unsigned u = __float_as_uint(row[i]);
            unsigned m = (u >> 31) ? ~u : (u | 0x80000000u);  // monotone map
            v[o] = ((ull)(~m) << 32) | (unsigned)i;
        } else {
            v[o] = PADKEY;
        }
    }

    for (int kk = 2; kk <= N8; kk <<= 1) {
        const int j0 = kk >> 1;
        // LDS stages: j >= 512 (cross-wave for 8 elems/thread)
        if (j0 >= 512) {
#pragma unroll
            for (int o = 0; o < E; ++o) sm.u.key[base + o] = v[o];
            __syncthreads();
            for (int j = j0; j >= 512; j >>= 1) {
#pragma unroll
                for (int it = 0; it < (N8 / 2) / T; ++it) {   // 4 pair-iters
                    int t  = tid + it * T;
                    int i  = ((t & ~(j - 1)) << 1) | (t & (j - 1));
                    int ix = i | j;
                    ull a = sm.u.key[i], c = sm.u.key[ix];
                    bool up = ((i & kk) == 0);
                    if ((a > c) == up) { sm.u.key[i] = c; sm.u.key[ix] = a; }
                }
                __syncthreads();
            }
#pragma unroll
            for (int o = 0; o < E; ++o) v[o] = sm.u.key[base + o];
        }
        // wave-shuffle stages: j = min(j0,256) .. 8 (lm = j/8 <= 32)
        int jstart = (j0 > 256) ? 256 : j0;
        for (int j = jstart; j >= E; j >>= 1) {
            int lm = j >> 3;
            // kk >= 16 whenever shuffle stages run -> up uniform over o
            bool takeMin = (((tid & lm) == 0) == ((base & kk) == 0));
#pragma unroll
            for (int o = 0; o < E; ++o) {
                ull c = shfl_xor64(v[o], lm);
                ull mn = (v[o] < c) ? v[o] : c;
                ull mx = (v[o] < c) ? c : v[o];
                v[o] = takeMin ? mn : mx;
            }
        }
        // register stages: j = 4, 2, 1 (within the 8-reg array)
#pragma unroll
        for (int j = 4; j >= 1; j >>= 1) {
            if (j < kk) {
#pragma unroll
                for (int o = 0; o < E; ++o) {
                    if ((o & j) == 0) {
                        bool up = (((base + o) & kk) == 0);
                        ull a = v[o], c = v[o | j];
                        if ((a > c) == up) { v[o] = c; v[o | j] = a; }
                    }
                }
            }
        }
    }

    // keys now fully sorted, held in regs. Barrier before aliasing writes.
    __syncthreads();

    // ---- Phase 2: decode + scatter (rank == position; real keys < PADKEY
    //      occupy exactly positions 0..G-1) ----
#pragma unroll
    for (int o = 0; o < E; ++o) {
        ull kv = v[o];
        if (kv != PADKEY) {
            int pos = base + o;                       // < G
            int idx = (int)(unsigned)(kv & 0xFFFFFFFFu);
            unsigned m = ~((unsigned)(kv >> 32));
            unsigned absbits = ((m >> 31) ? m : ~m) & 0x7FFFFFFFu;
            float av = __uint_as_float(absbits);
            sm.u.s.swq[pos]  = sqrtf(sqrtf(av));      // |v|^0.25
            sm.u.s.sm16[pos] = sm.pbwin[idx];
        }
    }
    __syncthreads();

    // ---- Phase 3: es (R3-verified structure) ----
    const int lane = tid & 63;
    const int w  = tid >> 6;        // 0..15
    const int qg = w >> 2;          // pathway quad 0..3
    const int h  = w & 3;           // gene quarter 0..3
    const int sh4 = qg * 4;         // shift within the 13-bit window

    const int lg = h * 64 + lane;   // global chunk id 0..255
    const int start = lg * LPW4;
    int cnt = G - start;
    cnt = (cnt < 0) ? 0 : ((cnt > LPW4) ? LPW4 : cnt);

    // Pass A: per-chunk (sum w*hit, #hit) for 4 pathways at once
    double sw[4] = {0.0, 0.0, 0.0, 0.0};
    int sh[4] = {0, 0, 0, 0};
    for (int k = 0; k < cnt; ++k) {
        int s = start + k;
        unsigned nib = ((unsigned)sm.u.s.sm16[s] >> sh4) & 15u;
        double wv = (double)sm.u.s.swq[s];
#pragma unroll
        for (int q = 0; q < 4; ++q) {
            if ((nib >> q) & 1u) { sw[q] += wv; sh[q]++; }
        }
    }
    // wave totals (this quarter) -> LDS
#pragma unroll
    for (int q = 0; q < 4; ++q) {
        double s_ = sw[q]; int c_ = sh[q];
#pragma unroll
        for (int off = 1; off < 64; off <<= 1) {
            s_ += __shfl_xor(s_, off, 64);
            c_ += __shfl_xor(c_, off, 64);
        }
        if (lane == 0) { sm.cSW[qg][h][q] = s_; sm.cSH[qg][h][q] = c_; }
    }
    __syncthreads();

    // Quarter gene counts: Qc[h'] = clamp(G - h'*1344, 0, 1344)
    int Qc[4];
#pragma unroll
    for (int hh = 0; hh < 4; ++hh) {
        int c = G - hh * QSPAN;
        Qc[hh] = (c < 0) ? 0 : ((c > QSPAN) ? QSPAN : c);
    }

    // Global totals + per-lane exclusive prefix (hierarchical quarter offset)
    double norm[4], inv_denom[4], running[4];
    int shtot[4];
#pragma unroll
    for (int q = 0; q < 4; ++q) {
        double st = 0.0; int ct = 0;
#pragma unroll
        for (int hh = 0; hh < 4; ++hh) { st += sm.cSW[qg][hh][q]; ct += sm.cSH[qg][hh][q]; }
        shtot[q]     = ct;
        norm[q]      = (st > 0.0) ? 1.0 / st : 1.0;
        inv_denom[q] = 1.0 / fmax((double)(G - ct), 1.0);
        double offq = 0.0;
        for (int hh = 0; hh < h; ++hh)
            offq += sm.cSW[qg][hh][q] * norm[q]
                  - (double)(Qc[hh] - sm.cSH[qg][hh][q]) * inv_denom[q];
        double csum = sw[q] * norm[q] - (double)(cnt - sh[q]) * inv_denom[q];
        double x = csum;
#pragma unroll
        for (int off = 1; off < 64; off <<= 1) {
            double vv = __shfl_up(x, off, 64);
            if (lane >= off) x += vv;
        }
        running[q] = x - csum + offq;
    }

    // Pass C: walk chunk, first-occurrence argmax of |running| (4 pathways)
    double bestv[4] = {-1.0, -1.0, -1.0, -1.0};
    double bestr[4] = {0.0, 0.0, 0.0, 0.0};
    int besti[4] = {0x7FFFFFFF, 0x7FFFFFFF, 0x7FFFFFFF, 0x7FFFFFFF};
    for (int k = 0; k < cnt; ++k) {
        int s = start + k;
        unsigned nib = ((unsigned)sm.u.s.sm16[s] >> sh4) & 15u;
        double wv = (double)sm.u.s.swq[s];
#pragma unroll
        for (int q = 0; q < 4; ++q) {
            running[q] += ((nib >> q) & 1u) ? wv * norm[q] : -inv_denom[q];
            double a = fabs(running[q]);
            if (a > bestv[q]) { bestv[q] = a; bestr[q] = running[q]; besti[q] = s; }
        }
    }
    // wave-level argmax reduce (first occurrence within quarter)
#pragma unroll
    for (int q = 0; q < 4; ++q) {
#pragma unroll
        for (int off = 1; off < 64; off <<= 1) {
            double ov  = __shfl_xor(bestv[q], off, 64);
            double orr = __shfl_xor(bestr[q], off, 64);
            int    oi  = __shfl_xor(besti[q], off, 64);
            if (ov > bestv[q] || (ov == bestv[q] && oi < besti[q])) {
                bestv[q] = ov; bestr[q] = orr; besti[q] = oi;
            }
        }
        if (lane == 0) { sm.cBV[qg][h][q] = bestv[q]; sm.cBR[qg][h][q] = bestr[q]; }
    }
    __syncthreads();

    // cross-quarter combine + write (quarter h covers strictly increasing
    // gene indices, so strict > keeps the first occurrence on ties)
    if (h == 0 && lane == 0) {
#pragma unroll
        for (int q = 0; q < 4; ++q) {
            double bv = sm.cBV[qg][0][q];
            double br = sm.cBR[qg][0][q];
#pragma unroll
            for (int hh = 1; hh < 4; ++hh) {
                double v_ = sm.cBV[qg][hh][q];
                if (v_ > bv) { bv = v_; br = sm.cBR[qg][hh][q]; }
            }
            int p = pbeg + sh4 + q;
            if (p < pend)
                out[(size_t)b * P + p] = (shtot[q] > 0) ? (float)br : 0.0f;
        }
    }
}

extern "C" void kernel_launch(void* const* d_in, const int* in_sizes, int n_in,
                              void* d_out, int out_size, void* d_ws, size_t ws_size,
                              hipStream_t stream) {
    const float* expr    = (const float*)d_in[0];   // [B, G]
    const float* pathway = (const float*)d_in[1];   // [P, G]
    float* out = (float*)d_out;                     // [B, P]
    (void)d_ws; (void)ws_size;                      // no workspace needed

    mono_es<<<dim3(4, Bc), dim3(T), 0, stream>>>(
        expr, pathway, out, Bc, Pc, Gc);
}

// Round 5
// 116.311 us; speedup vs baseline: 1.3558x; 1.3558x over previous
//
#include <hip/hip_runtime.h>
#include <math.h>

typedef unsigned long long ull;

// Problem constants (from setup_inputs): B=64, G=4999, P=50
constexpr int Bc = 64;
constexpr int Gc = 4999;
constexpr int Pc = 50;

constexpr int RUN   = 1024;          // elements per sorted run
constexpr int NRUN  = 5;             // runs per row (5*1024 = 5120 >= G)
constexpr int NPAD  = NRUN * RUN;
constexpr int NCHUNK = NRUN * Bc;    // 320 wave-sorts
constexpr int EW   = 16;             // elems per lane in wave_sort
constexpr int LPW  = 41;             // genes per lane in es phase (128 chunks * 41 = 5248 >= G; 41 coprime 32 banks)
constexpr int HALF0 = 64 * LPW;      // genes covered by half 0 = 2624 (< G)
constexpr ull PADKEY = 0xFFFFFFFFFFFFFFFFull;

__device__ __forceinline__ ull shfl_xor64(ull v, int lm) {
    int lo = __shfl_xor((int)(unsigned)(v & 0xFFFFFFFFull), lm, 64);
    int hi = __shfl_xor((int)(unsigned)(v >> 32), lm, 64);
    return ((ull)(unsigned)hi << 32) | (unsigned)lo;
}

// ---------------------------------------------------------------------------
// Kernel 1: SINGLE-WAVE chunk sort. Each wave sorts one 1024-chunk with 16
// elems/lane: register stages j<=8, wave-shuffle stages j=16..512
// (lane-mask j/16 <= 32, always intra-wave). ZERO LDS stages, ZERO barriers
// — removes the LDS-pipe serialization + block stragglers that made the
// 256-thr version 18.8 us. 4 independent wave-sorts per 256-thr block ->
// 80 blocks (<=1/CU). key = (~m)<<32 | idx (unique): ascending u64 ==
// descending value, stable by index (== stable argsort(-x)).
// Blocks 0..19 also pack pathway bits (proven structure, g = x*256+tid).
// ---------------------------------------------------------------------------
__global__ __launch_bounds__(256) void wave_sort(
    const float* __restrict__ expr, const float* __restrict__ pathway,
    ull* __restrict__ runs, ull* __restrict__ pbits, int P, int G)
{
    const int tid  = threadIdx.x;
    const int lane = tid & 63;
    const int w    = tid >> 6;

    // Folded pathway pack: blocks 0..19 (20*256 = 5120 >= G), coalesced over g.
    {
        int g = blockIdx.x * 256 + tid;
        if (g < G) {
            ull m = 0;
#pragma unroll
            for (int p = 0; p < Pc; ++p)
                if (pathway[(size_t)p * G + g] > 0.0f) m |= (1ull << p);
            pbits[g] = m;
        }
    }

    const int C = blockIdx.x * 4 + w;      // chunk id 0..319
    const int b = C / NRUN, r = C % NRUN;
    const int base = lane * EW;            // within-chunk offset
    const float* row = expr + (size_t)b * G;
    const int gbase = r * RUN + base;      // global gene index of elem 0

    ull v[EW];
    if (gbase + EW <= G) {
        // fast path: 4x float4 coalesced (lane-strided 64B)
        const float4* row4 = (const float4*)(row + r * RUN);
#pragma unroll
        for (int f = 0; f < 4; ++f) {
            float4 x = row4[lane * 4 + f];
            float xs[4] = {x.x, x.y, x.z, x.w};
#pragma unroll
            for (int c = 0; c < 4; ++c) {
                int o = f * 4 + c;
                unsigned u = __float_as_uint(xs[c]);
                unsigned m = (u >> 31) ? ~u : (u | 0x80000000u);
                v[o] = ((ull)(~m) << 32) | (unsigned)(gbase + o);
            }
        }
    } else {
#pragma unroll
        for (int o = 0; o < EW; ++o) {
            int i = gbase + o;
            if (i < G) {
                unsigned u = __float_as_uint(row[i]);
                unsigned m = (u >> 31) ? ~u : (u | 0x80000000u);
                v[o] = ((ull)(~m) << 32) | (unsigned)i;
            } else {
                v[o] = PADKEY;
            }
        }
    }

    // bitonic sort of 1024 = 64 lanes x 16 elems, fully intra-wave
#pragma unroll 1
    for (int kk = 2; kk <= RUN; kk <<= 1) {
        const int j0 = kk >> 1;
        // shuffle stages: j = min(j0,512) .. 16  (lm = j/16 in 1..32)
        int jstart = (j0 > 512) ? 512 : j0;
        for (int j = jstart; j >= EW; j >>= 1) {
            int lm = j >> 4;
            // kk >= 32 here -> (i & kk) uniform over o: depends on lane only
            bool takeMin = (((lane & lm) == 0) == ((base & kk) == 0));
#pragma unroll
            for (int o = 0; o < EW; ++o) {
                ull c = shfl_xor64(v[o], lm);
                ull mn = (v[o] < c) ? v[o] : c;
                ull mx = (v[o] < c) ? c : v[o];
                v[o] = takeMin ? mn : mx;
            }
        }
        // register stages: j = 8..1 within the 16-elem array
        for (int j = 8; j >= 1; j >>= 1) {
            if (j < kk) {
#pragma unroll
                for (int o = 0; o < EW; ++o) {
                    if ((o & j) == 0) {
                        bool up = (((base + o) & kk) == 0);
                        ull a = v[o], c = v[o | j];
                        if ((a > c) == up) { v[o] = c; v[o | j] = a; }
                    }
                }
            }
        }
    }

    // store sorted run (ulonglong2 pairs, 16B aligned)
    ulonglong2* dst2 = (ulonglong2*)(runs + (size_t)C * RUN);
#pragma unroll
    for (int o = 0; o < EW; o += 2) {
        ulonglong2 t; t.x = v[o]; t.y = v[o + 1];
        dst2[lane * (EW / 2) + o / 2] = t;
    }
}

// ---------------------------------------------------------------------------
// Kernel 2: rank + scatter (R1-verified). Grid (5,64) x 1024: block (rg,b)
// stages all 5 runs (40 KB LDS) and ranks elements [rg*1024, rg*1024+1024),
// one per thread: rank = own-run pos + 4 binary searches. Keys unique ->
// exact bijection onto [0,G). NEW: single fused 16B scatter (pb | wq bits)
// instead of separate 8B+4B scatters.
// ---------------------------------------------------------------------------
__global__ __launch_bounds__(1024) void rank_scatter(
    const ull* __restrict__ runs, const ull* __restrict__ pbits,
    ulonglong2* __restrict__ wp, int G)
{
    __shared__ ull runsLDS[NPAD];   // 40960 B
    const int rg = blockIdx.x, b = blockIdx.y, tid = threadIdx.x;

    const ull* rowruns = runs + (size_t)b * NPAD;
    for (int i = tid; i < NPAD; i += 1024) runsLDS[i] = rowruns[i];
    __syncthreads();

    const int e = rg * 1024 + tid;          // 0..5119
    const ull keyv = runsLDS[e];
    if (keyv == PADKEY) return;             // padding

    // issue the pbits load early — independent of the rank computation
    const int idx = (int)(unsigned)(keyv & 0xFFFFFFFFu);
    const ull pb = pbits[idx];

    const int run = e >> 10;                // e / 1024
    int rank = e & 1023;                    // own-run position (stable)
#pragma unroll
    for (int rr = 0; rr < NRUN; ++rr) {
        if (rr == run) continue;
        const ull* arr = &runsLDS[rr * RUN];
        int pos = 0;
#pragma unroll
        for (int s = RUN; s >= 1; s >>= 1) {
            int np = pos + s;
            if (np <= RUN && arr[np - 1] < keyv) pos = np;
        }
        rank += pos;                        // # elements < keyv
    }

    unsigned m = ~((unsigned)(keyv >> 32));
    unsigned absbits = ((m >> 31) ? m : ~m) & 0x7FFFFFFFu;
    float av = __uint_as_float(absbits);
    ulonglong2 t;
    t.x = pb;
    t.y = (ull)__float_as_uint(sqrtf(sqrtf(av)));   // |v|^0.25
    wp[(size_t)b * G + rank] = t;
}

// ---------------------------------------------------------------------------
// Kernel 3: enrichment scores (R1-verified half-split). Grid (4,64) x 512
// (8 waves): block (pg,b) handles pathways [pg*13, ...). Wave w: pathway
// quad qg=w>>1 x gene half h=w&1; lane chunk 41 genes (41 coprime 32 banks
// -> conflict-free). Staging reads the fused 16B struct (coalesced).
// ---------------------------------------------------------------------------
__global__ __launch_bounds__(512) void es_kernel(
    const ulonglong2* __restrict__ wp, float* __restrict__ out,
    int B, int P, int G)
{
    __shared__ float    swq[Gc];     // 19996 B
    __shared__ unsigned sm32[Gc];    // 19996 B
    __shared__ double   cSW[4][2][4];
    __shared__ int      cSH[4][2][4];
    __shared__ double   cBV[4][2][4];
    __shared__ double   cBR[4][2][4];

    const int pg = blockIdx.x;
    const int b  = blockIdx.y;
    const int tid = threadIdx.x;
    const int pbeg = pg * 13;
    const int pend = (pbeg + 13 < P) ? (pbeg + 13) : P;

    for (int i = tid; i < G; i += 512) {
        ulonglong2 t = wp[(size_t)b * G + i];
        swq[i]  = __uint_as_float((unsigned)t.y);
        sm32[i] = (unsigned)(t.x >> pbeg);
    }
    __syncthreads();

    const int lane = tid & 63;
    const int w  = tid >> 6;        // 0..7
    const int qg = w >> 1;          // pathway quad 0..3
    const int h  = w & 1;           // gene half 0/1
    const int sh4 = qg * 4;         // shift within the 13-bit window

    const int lg = h * 64 + lane;   // global chunk id 0..127
    const int start = lg * LPW;
    int cnt = G - start;
    cnt = (cnt < 0) ? 0 : ((cnt > LPW) ? LPW : cnt);

    // Pass A: per-chunk (sum w*hit, #hit) for 4 pathways at once
    double sw[4] = {0.0, 0.0, 0.0, 0.0};
    int sh[4] = {0, 0, 0, 0};
    for (int k = 0; k < cnt; ++k) {
        int s = start + k;
        unsigned nib = (sm32[s] >> sh4) & 15u;
        double wv = (double)swq[s];
#pragma unroll
        for (int q = 0; q < 4; ++q) {
            if ((nib >> q) & 1u) { sw[q] += wv; sh[q]++; }
        }
    }
    // wave totals (this half) -> LDS
#pragma unroll
    for (int q = 0; q < 4; ++q) {
        double s_ = sw[q]; int c_ = sh[q];
#pragma unroll
        for (int off = 1; off < 64; off <<= 1) {
            s_ += __shfl_xor(s_, off, 64);
            c_ += __shfl_xor(c_, off, 64);
        }
        if (lane == 0) { cSW[qg][h][q] = s_; cSH[qg][h][q] = c_; }
    }
    __syncthreads();

    // Global totals + per-lane exclusive prefix (with half-1 offset)
    double norm[4], inv_denom[4], running[4];
    int shtot[4];
#pragma unroll
    for (int q = 0; q < 4; ++q) {
        double s0 = cSW[qg][0][q], s1 = cSW[qg][1][q];
        int    c0 = cSH[qg][0][q], c1 = cSH[qg][1][q];
        double st = s0 + s1;
        int    ct = c0 + c1;
        shtot[q]     = ct;
        norm[q]      = (st > 0.0) ? 1.0 / st : 1.0;
        inv_denom[q] = 1.0 / fmax((double)(G - ct), 1.0);
        // prefix offset for half 1 = running total after half 0 (2624 genes)
        double off1 = s0 * norm[q] - (double)(HALF0 - c0) * inv_denom[q];
        double csum = sw[q] * norm[q] - (double)(cnt - sh[q]) * inv_denom[q];
        double x = csum;
#pragma unroll
        for (int off = 1; off < 64; off <<= 1) {
            double vv = __shfl_up(x, off, 64);
            if (lane >= off) x += vv;
        }
        running[q] = x - csum + (h ? off1 : 0.0);
    }

    // Pass C: walk chunk, first-occurrence argmax of |running| (4 pathways)
    double bestv[4] = {-1.0, -1.0, -1.0, -1.0};
    double bestr[4] = {0.0, 0.0, 0.0, 0.0};
    int besti[4] = {0x7FFFFFFF, 0x7FFFFFFF, 0x7FFFFFFF, 0x7FFFFFFF};
    for (int k = 0; k < cnt; ++k) {
        int s = start + k;
        unsigned nib = (sm32[s] >> sh4) & 15u;
        double wv = (double)swq[s];
#pragma unroll
        for (int q = 0; q < 4; ++q) {
            running[q] += ((nib >> q) & 1u) ? wv * norm[q] : -inv_denom[q];
            double a = fabs(running[q]);
            if (a > bestv[q]) { bestv[q] = a; bestr[q] = running[q]; besti[q] = s; }
        }
    }
    // wave-level argmax reduce (first occurrence within half)
#pragma unroll
    for (int q = 0; q < 4; ++q) {
#pragma unroll
        for (int off = 1; off < 64; off <<= 1) {
            double ov  = __shfl_xor(bestv[q], off, 64);
            double orr = __shfl_xor(bestr[q], off, 64);
            int    oi  = __shfl_xor(besti[q], off, 64);
            if (ov > bestv[q] || (ov == bestv[q] && oi < besti[q])) {
                bestv[q] = ov; bestr[q] = orr; besti[q] = oi;
            }
        }
        if (lane == 0) { cBV[qg][h][q] = bestv[q]; cBR[qg][h][q] = bestr[q]; }
    }
    __syncthreads();

    // cross-half combine + write (half-0 indices always < half-1 indices,
    // so strict > keeps the first occurrence on ties)
    if (h == 0 && lane == 0) {
#pragma unroll
        for (int q = 0; q < 4; ++q) {
            double v0 = cBV[qg][0][q], v1 = cBV[qg][1][q];
            double r_ = (v1 > v0) ? cBR[qg][1][q] : cBR[qg][0][q];
            int p = pbeg + sh4 + q;
            if (p < pend)
                out[(size_t)b * P + p] = (shtot[q] > 0) ? (float)r_ : 0.0f;
        }
    }
}

extern "C" void kernel_launch(void* const* d_in, const int* in_sizes, int n_in,
                              void* d_out, int out_size, void* d_ws, size_t ws_size,
                              hipStream_t stream) {
    const float* expr    = (const float*)d_in[0];   // [B, G]
    const float* pathway = (const float*)d_in[1];   // [P, G]
    float* out = (float*)d_out;                     // [B, P]

    // workspace layout (bytes):
    //   pbits ull[5120]        @ 0        (40960)
    //   runs  ull[320*1024]    @ 40960    (2621440 -> ends 2662400)
    //   wp    ull2[B*G]        @ 2662400  (5118976 -> ends 7781376)  ~7.8 MB
    char* ws = (char*)d_ws;
    ull*        pbits = (ull*)ws;
    ull*        runs  = (ull*)(ws + 40960);
    ulonglong2* wp    = (ulonglong2*)(ws + 2662400);

    wave_sort<<<dim3(NCHUNK / 4), dim3(256), 0, stream>>>(
        expr, pathway, runs, pbits, Pc, Gc);
    rank_scatter<<<dim3(NRUN, Bc), dim3(1024), 0, stream>>>(runs, pbits, wp, Gc);
    es_kernel<<<dim3(4, Bc), dim3(512), 0, stream>>>(
        wp, out, Bc, Pc, Gc);
}

// Round 6
// 103.864 us; speedup vs baseline: 1.5183x; 1.1198x over previous
//
#include <hip/hip_runtime.h>
#include <math.h>

typedef unsigned long long ull;

// Problem constants (from setup_inputs): B=64, G=4999, P=50
constexpr int Bc = 64;
constexpr int Gc = 4999;
constexpr int Pc = 50;

constexpr int RUN   = 1024;          // elements per sorted run
constexpr int NRUN  = 5;             // runs per row (5*1024 = 5120 >= G)
constexpr int NPAD  = NRUN * RUN;
constexpr int LPW4  = 21;            // genes per lane in es phase
constexpr int PADG  = 256 * LPW4;    // padded gene count = 5376
constexpr int QSPAN = 64 * LPW4;     // genes per quarter = 1344
constexpr ull PADKEY = 0xFFFFFFFFFFFFFFFFull;

__device__ __forceinline__ ull shfl_xor64(ull v, int lm) {
    int lo = __shfl_xor((int)(unsigned)(v & 0xFFFFFFFFull), lm, 64);
    int hi = __shfl_xor((int)(unsigned)(v >> 32), lm, 64);
    return ((ull)(unsigned)hi << 32) | (unsigned)lo;
}

// ---------------------------------------------------------------------------
// Kernel 1: sort one 1024-element chunk of one row (R1-proven, ~19 us).
// 256 thr, 4 elems/thread. key = (~m)<<32 | idx (unique): ascending u64 ==
// descending value, stable by index (== stable argsort(-x)).
// Blocks with r==0 also pack pathway bits (consumed by next launch — safe).
// ---------------------------------------------------------------------------
__global__ __launch_bounds__(256) void chunk_sort(
    const float* __restrict__ expr, const float* __restrict__ pathway,
    ull* __restrict__ runs, ull* __restrict__ pbits, int P, int G)
{
    __shared__ ull key[RUN];
    const int r = blockIdx.x, b = blockIdx.y, tid = threadIdx.x;
    const int base = tid * 4;
    const float* row = expr + (size_t)b * G;

    ull v[4];
#pragma unroll
    for (int o = 0; o < 4; ++o) {
        int i = r * RUN + base + o;
        if (i < G) {
            unsigned u = __float_as_uint(row[i]);
            unsigned m = (u >> 31) ? ~u : (u | 0x80000000u);  // monotone map
            v[o] = ((ull)(~m) << 32) | (unsigned)i;
        } else {
            v[o] = PADKEY;
        }
    }

    for (int kk = 2; kk <= RUN; kk <<= 1) {
        const int j0 = kk >> 1;
        if (j0 >= 256) {
#pragma unroll
            for (int o = 0; o < 4; ++o) key[base + o] = v[o];
            __syncthreads();
            for (int j = j0; j >= 256; j >>= 1) {
#pragma unroll
                for (int t = tid; t < RUN / 2; t += 256) {
                    int i  = ((t & ~(j - 1)) << 1) | (t & (j - 1));
                    int ix = i | j;
                    ull a = key[i], c = key[ix];
                    bool up = ((i & kk) == 0);
                    if ((a > c) == up) { key[i] = c; key[ix] = a; }
                }
                __syncthreads();
            }
#pragma unroll
            for (int o = 0; o < 4; ++o) v[o] = key[base + o];
        }
        int jstart = (j0 > 128) ? 128 : j0;
        for (int j = jstart; j >= 4; j >>= 1) {
            int lm = j >> 2;
            bool takeMin = (((tid & lm) == 0) == ((base & kk) == 0));
#pragma unroll
            for (int o = 0; o < 4; ++o) {
                ull c = shfl_xor64(v[o], lm);
                ull mn = (v[o] < c) ? v[o] : c;
                ull mx = (v[o] < c) ? c : v[o];
                v[o] = takeMin ? mn : mx;
            }
        }
#pragma unroll
        for (int j = 2; j >= 1; j >>= 1) {
            if (j < kk) {
#pragma unroll
                for (int o = 0; o < 4; ++o) {
                    if ((o & j) == 0) {
                        bool up = (((base + o) & kk) == 0);
                        ull a = v[o], c = v[o | j];
                        if ((a > c) == up) { v[o] = c; v[o | j] = a; }
                    }
                }
            }
        }
    }

    ull* dst = runs + ((size_t)b * NRUN + r) * RUN;
#pragma unroll
    for (int o = 0; o < 4; ++o) dst[base + o] = v[o];

    if (r == 0) {
        int g = b * 256 + tid;
        if (g < G) {
            ull m = 0;
#pragma unroll
            for (int p = 0; p < Pc; ++p)
                if (pathway[(size_t)p * G + g] > 0.0f) m |= (1ull << p);
            pbits[g] = m;
        }
    }
}

// ---------------------------------------------------------------------------
// Kernel 2: rank + scatter (R5-verified fused 16B write). Grid (5,64) x 1024:
// block (rg,b) stages all 5 runs (40 KB LDS) and ranks elements
// [rg*1024, rg*1024+1024), one per thread: rank = own-run pos + 4 binary
// searches. Keys unique -> exact bijection onto [0,G). Single fused 16B
// scatter: wp[rank] = { pbits[idx], |v|^0.25 bits }.
// ---------------------------------------------------------------------------
__global__ __launch_bounds__(1024) void rank_scatter(
    const ull* __restrict__ runs, const ull* __restrict__ pbits,
    ulonglong2* __restrict__ wp, int G)
{
    __shared__ ull runsLDS[NPAD];   // 40960 B
    const int rg = blockIdx.x, b = blockIdx.y, tid = threadIdx.x;

    const ull* rowruns = runs + (size_t)b * NPAD;
    for (int i = tid; i < NPAD; i += 1024) runsLDS[i] = rowruns[i];
    __syncthreads();

    const int e = rg * 1024 + tid;          // 0..5119
    const ull keyv = runsLDS[e];
    if (keyv == PADKEY) return;             // padding

    const int idx = (int)(unsigned)(keyv & 0xFFFFFFFFu);
    const ull pb = pbits[idx];              // issued early, hides under searches

    const int run = e >> 10;
    int rank = e & 1023;                    // own-run position (stable)
#pragma unroll
    for (int rr = 0; rr < NRUN; ++rr) {
        if (rr == run) continue;
        const ull* arr = &runsLDS[rr * RUN];
        int pos = 0;
#pragma unroll
        for (int s = RUN; s >= 1; s >>= 1) {
            int np = pos + s;
            if (np <= RUN && arr[np - 1] < keyv) pos = np;
        }
        rank += pos;
    }

    unsigned m = ~((unsigned)(keyv >> 32));
    unsigned absbits = ((m >> 31) ? m : ~m) & 0x7FFFFFFFu;
    float av = __uint_as_float(absbits);
    ulonglong2 t;
    t.x = pb;
    t.y = (ull)__float_as_uint(sqrtf(sqrtf(av)));   // |v|^0.25
    wp[(size_t)b * G + rank] = t;
}

// ---------------------------------------------------------------------------
// Kernel 3: enrichment scores, THROUGHPUT rewrite. Grid (4,64) x 1024
// (16 waves): wave w = pathway quad qg=w>>2 x gene quarter h=w&3 (R3-proven
// decomposition). Two new levers:
//   (1) norm-factored scan: running' = running/norm; step = hit ? wv : -e[q]
//       with e[q] = inv_denom[q]*sum_w — removes the per-(iter,q) f64 mul;
//       result rescaled once at the end (argmax invariant under positive
//       scaling; norm > 0 always).
//   (2) LDS padded to 5376: pads get {wv=0, bits=all-ones} -> zero-step hits.
//       Loop bound becomes the COMPILE-TIME constant 21 -> full unroll,
//       pipelined LDS loads, no per-iter branch. Hit counts corrected by
//       per-lane npads; pad candidates can only TIE the real running value
//       at G-1 and lose the index tie-break (strict >, earlier index wins).
// ---------------------------------------------------------------------------
__global__ __launch_bounds__(1024) void es_kernel(
    const ulonglong2* __restrict__ wp, float* __restrict__ out,
    int B, int P, int G)
{
    __shared__ float    swq[PADG];   // 21504 B
    __shared__ unsigned sm32[PADG];  // 21504 B
    __shared__ double   cSW[4][4][4];
    __shared__ int      cSH[4][4][4];
    __shared__ double   cBV[4][4][4];
    __shared__ double   cBR[4][4][4];

    const int pg = blockIdx.x;
    const int b  = blockIdx.y;
    const int tid = threadIdx.x;
    const int pbeg = pg * 13;
    const int pend = (pbeg + 13 < P) ? (pbeg + 13) : P;

    for (int i = tid; i < PADG; i += 1024) {
        if (i < G) {
            ulonglong2 t = wp[(size_t)b * G + i];
            swq[i]  = __uint_as_float((unsigned)t.y);
            sm32[i] = (unsigned)(t.x >> pbeg);
        } else {
            swq[i]  = 0.0f;
            sm32[i] = 0xFFFFFFFFu;          // pad = all-hit with wv=0
        }
    }
    __syncthreads();

    const int lane = tid & 63;
    const int w  = tid >> 6;        // 0..15
    const int qg = w >> 2;          // pathway quad 0..3
    const int h  = w & 3;           // gene quarter 0..3
    const int sh4 = qg * 4;

    const int lg = h * 64 + lane;   // chunk id 0..255
    const int start = lg * LPW4;
    int npads = start + LPW4 - G;
    npads = (npads < 0) ? 0 : ((npads > LPW4) ? LPW4 : npads);

    // Pass A: per-chunk (sum w*hit, #hit incl. pads), constant-bound unrolled
    double sw[4] = {0.0, 0.0, 0.0, 0.0};
    int shl[4] = {0, 0, 0, 0};
#pragma unroll
    for (int k = 0; k < LPW4; ++k) {
        int s = start + k;
        unsigned b4 = sm32[s] >> sh4;
        double wv = (double)swq[s];
#pragma unroll
        for (int q = 0; q < 4; ++q) {
            if ((b4 >> q) & 1u) { sw[q] += wv; shl[q]++; }
        }
    }
    // wave totals (real hit counts = shl - npads) -> LDS
#pragma unroll
    for (int q = 0; q < 4; ++q) {
        double s_ = sw[q]; int c_ = shl[q] - npads;
#pragma unroll
        for (int off = 1; off < 64; off <<= 1) {
            s_ += __shfl_xor(s_, off, 64);
            c_ += __shfl_xor(c_, off, 64);
        }
        if (lane == 0) { cSW[qg][h][q] = s_; cSH[qg][h][q] = c_; }
    }
    __syncthreads();

    // Quarter gene counts (real): Qc[h'] = clamp(G - h'*1344, 0, 1344)
    int Qc[4];
#pragma unroll
    for (int hh = 0; hh < 4; ++hh) {
        int c = G - hh * QSPAN;
        Qc[hh] = (c < 0) ? 0 : ((c > QSPAN) ? QSPAN : c);
    }

    // Totals, norm-factored constants, per-lane exclusive prefix
    double negE[4], normq[4], runn[4];
    int shtot[4];
#pragma unroll
    for (int q = 0; q < 4; ++q) {
        double st = 0.0; int ct = 0;
#pragma unroll
        for (int hh = 0; hh < 4; ++hh) { st += cSW[qg][hh][q]; ct += cSH[qg][hh][q]; }
        shtot[q] = ct;
        double d = 1.0 / fmax((double)(G - ct), 1.0);     // inv_denom
        double e = (st > 0.0) ? d * st : d;               // e = inv_denom/norm
        negE[q]  = -e;
        normq[q] = (st > 0.0) ? 1.0 / st : 1.0;
        // offset for this quarter (running' scale)
        double offq = 0.0;
        for (int hh = 0; hh < h; ++hh)
            offq += cSW[qg][hh][q] - (double)(Qc[hh] - cSH[qg][hh][q]) * e;
        // per-lane chunk sum (pads contribute 0; in-loop misses = 21 - shl)
        double csum = sw[q] - (double)(LPW4 - shl[q]) * e;
        double x = csum;
#pragma unroll
        for (int off = 1; off < 64; off <<= 1) {
            double vv = __shfl_up(x, off, 64);
            if (lane >= off) x += vv;
        }
        runn[q] = x - csum + offq;          // exclusive prefix + quarter offset
    }

    // Pass C: constant-bound unrolled scan, no muls in the body
    double bestv[4] = {-1.0, -1.0, -1.0, -1.0};
    double bestr[4] = {0.0, 0.0, 0.0, 0.0};
    int besti[4] = {0x7FFFFFFF, 0x7FFFFFFF, 0x7FFFFFFF, 0x7FFFFFFF};
#pragma unroll
    for (int k = 0; k < LPW4; ++k) {
        int s = start + k;
        unsigned b4 = sm32[s] >> sh4;
        double wv = (double)swq[s];
#pragma unroll
        for (int q = 0; q < 4; ++q) {
            runn[q] += ((b4 >> q) & 1u) ? wv : negE[q];
            double a = fabs(runn[q]);
            if (a > bestv[q]) { bestv[q] = a; bestr[q] = runn[q]; besti[q] = s; }
        }
    }
    // wave-level argmax reduce (first occurrence within quarter)
#pragma unroll
    for (int q = 0; q < 4; ++q) {
#pragma unroll
        for (int off = 1; off < 64; off <<= 1) {
            double ov  = __shfl_xor(bestv[q], off, 64);
            double orr = __shfl_xor(bestr[q], off, 64);
            int    oi  = __shfl_xor(besti[q], off, 64);
            if (ov > bestv[q] || (ov == bestv[q] && oi < besti[q])) {
                bestv[q] = ov; bestr[q] = orr; besti[q] = oi;
            }
        }
        if (lane == 0) { cBV[qg][h][q] = bestv[q]; cBR[qg][h][q] = bestr[q]; }
    }
    __syncthreads();

    // cross-quarter combine + rescale + write (quarters ordered by gene
    // index, so strict > keeps the first occurrence on ties)
    if (h == 0 && lane == 0) {
#pragma unroll
        for (int q = 0; q < 4; ++q) {
            double bv = cBV[qg][0][q];
            double br = cBR[qg][0][q];
#pragma unroll
            for (int hh = 1; hh < 4; ++hh) {
                double v_ = cBV[qg][hh][q];
                if (v_ > bv) { bv = v_; br = cBR[qg][hh][q]; }
            }
            int p = pbeg + sh4 + q;
            if (p < pend)
                out[(size_t)b * P + p] =
                    (shtot[q] > 0) ? (float)(br * normq[q]) : 0.0f;
        }
    }
}

extern "C" void kernel_launch(void* const* d_in, const int* in_sizes, int n_in,
                              void* d_out, int out_size, void* d_ws, size_t ws_size,
                              hipStream_t stream) {
    const float* expr    = (const float*)d_in[0];   // [B, G]
    const float* pathway = (const float*)d_in[1];   // [P, G]
    float* out = (float*)d_out;                     // [B, P]

    // workspace layout (bytes):
    //   pbits ull[5120]        @ 0        (40960)
    //   runs  ull[320*1024]    @ 40960    (2621440 -> ends 2662400)
    //   wp    ull2[B*G]        @ 2662400  (5118976 -> ends 7781376)  ~7.8 MB
    char* ws = (char*)d_ws;
    ull*        pbits = (ull*)ws;
    ull*        runs  = (ull*)(ws + 40960);
    ulonglong2* wp    = (ulonglong2*)(ws + 2662400);

    chunk_sort<<<dim3(NRUN, Bc), dim3(256), 0, stream>>>(
        expr, pathway, runs, pbits, Pc, Gc);
    rank_scatter<<<dim3(NRUN, Bc), dim3(1024), 0, stream>>>(runs, pbits, wp, Gc);
    es_kernel<<<dim3(4, Bc), dim3(1024), 0, stream>>>(
        wp, out, Bc, Pc, Gc);
}